// Round 4
// baseline (185.266 us; speedup 1.0000x reference)
//
#include <hip/hip_runtime.h>

#define MAX_L 2048   // max phonemes per batch for LDS cumsum
#define MAX_EPC 8    // max cum elements per thread (L <= 256*8)

// Kernel 1: per-frame source row index into d_ws.
// One 256-thread block per 256 output frames (requires T % 256 == 0).
// widx[b*T + t] = (t < total_b) ? b*L + searchsorted(cum_b, t, 'right') : -1
__global__ __launch_bounds__(256) void lr_index_kernel(
        const int* __restrict__ dur,
        const int* __restrict__ tlen,
        int* __restrict__ widx,
        int BL, int BT) {
    const int T = *tlen;
    const int B = BT / T;
    const int L = BL / B;

    __shared__ int sc[MAX_L];
    __shared__ int swsum[4];

    const int frame_base = blockIdx.x * 256;
    if (frame_base >= BT) return;
    const int b  = frame_base / T;     // block never straddles a batch (T%256==0)
    const int t0 = frame_base - b * T;

    const int tid  = threadIdx.x;
    const int lane = tid & 63;
    const int wv   = tid >> 6;

    // ---- cumsum of this batch's duration row (registers + shuffle scan) ----
    const int epc  = (L + blockDim.x - 1) / blockDim.x;
    const int base = tid * epc;
    const int* __restrict__ drow = dur + (size_t)b * L;

    int local[MAX_EPC];
    int run = 0;
#pragma unroll
    for (int e = 0; e < MAX_EPC; ++e) {
        int v = 0;
        if (e < epc && base + e < L) v = drow[base + e];
        run += v;
        local[e] = run;
    }
    int ws = run;
#pragma unroll
    for (int off = 1; off < 64; off <<= 1) {
        int up = __shfl_up(ws, off, 64);
        if (lane >= off) ws += up;
    }
    if (lane == 63) swsum[wv] = ws;
    __syncthreads();
    int wprefix = 0;
    for (int w = 0; w < wv; ++w) wprefix += swsum[w];
    const int chunk_prefix = wprefix + ws - run;
#pragma unroll
    for (int e = 0; e < MAX_EPC; ++e)
        if (e < epc && base + e < L) sc[base + e] = chunk_prefix + local[e];
    __syncthreads();

    const int total = sc[L - 1];

    // ---- one search per thread, one coalesced index store ----
    const int f = frame_base + tid;
    if (f < BT) {
        const int t = t0 + tid;
        int p = -1;
        if (t < total) {
            int lo = 0, hi = L - 1;
            while (lo < hi) {
                const int mid = (lo + hi) >> 1;
                if (sc[mid] > t) hi = mid;
                else             lo = mid + 1;
            }
            p = b * L + lo;
        }
        widx[f] = p;
    }
}

// Kernel 2: pure streaming gather-copy, memcpy-shaped.
// Thread handles float4 g of the output; frame = g >> shift (wave-uniform),
// unconditional source load (row clamped to 0) + select against zero.
// 4-way unroll -> 4 independent load->store pairs in flight per thread.
__global__ __launch_bounds__(256) void lr_copy_kernel(
        const float4* __restrict__ fb,
        const int* __restrict__ widx,
        float4* __restrict__ ob,
        long n, int shift) {
    const long stride = (long)gridDim.x * blockDim.x;
    const int  mask   = (1 << shift) - 1;
    const float4 z = make_float4(0.f, 0.f, 0.f, 0.f);

    long g = (long)blockIdx.x * blockDim.x + threadIdx.x;
    for (; g + 3 * stride < n; g += 4 * stride) {
        const long g0 = g, g1 = g + stride, g2 = g + 2 * stride, g3 = g + 3 * stride;
        const int r0 = widx[g0 >> shift];
        const int r1 = widx[g1 >> shift];
        const int r2 = widx[g2 >> shift];
        const int r3 = widx[g3 >> shift];
        float4 v0 = fb[((long)max(r0, 0) << shift) + (int)(g0 & mask)];
        float4 v1 = fb[((long)max(r1, 0) << shift) + (int)(g1 & mask)];
        float4 v2 = fb[((long)max(r2, 0) << shift) + (int)(g2 & mask)];
        float4 v3 = fb[((long)max(r3, 0) << shift) + (int)(g3 & mask)];
        ob[g0] = (r0 >= 0) ? v0 : z;
        ob[g1] = (r1 >= 0) ? v1 : z;
        ob[g2] = (r2 >= 0) ? v2 : z;
        ob[g3] = (r3 >= 0) ? v3 : z;
    }
    for (; g < n; g += stride) {
        const int r = widx[g >> shift];
        float4 v = fb[((long)max(r, 0) << shift) + (int)(g & mask)];
        ob[g] = (r >= 0) ? v : z;
    }
}

// Generic (non-pow2 D/4) fallback — same structure, runtime div/mod.
__global__ __launch_bounds__(256) void lr_copy_generic_kernel(
        const float4* __restrict__ fb,
        const int* __restrict__ widx,
        float4* __restrict__ ob,
        long n, int vecs) {
    const long stride = (long)gridDim.x * blockDim.x;
    const float4 z = make_float4(0.f, 0.f, 0.f, 0.f);
    for (long g = (long)blockIdx.x * blockDim.x + threadIdx.x; g < n; g += stride) {
        const long frame = g / vecs;
        const int  off   = (int)(g - frame * vecs);
        const int  r     = widx[frame];
        float4 v = fb[(long)max(r, 0) * vecs + off];
        ob[g] = (r >= 0) ? v : z;
    }
}

extern "C" void kernel_launch(void* const* d_in, const int* in_sizes, int n_in,
                              void* d_out, int out_size, void* d_ws, size_t ws_size,
                              hipStream_t stream) {
    const float* feat = (const float*)d_in[0];   // [B, L, D] fp32
    const int*   dur  = (const int*)d_in[1];     // [B, L] int32
    const int*   tlen = (const int*)d_in[2];     // scalar target_length (device)

    const int BL = in_sizes[1];                  // B*L
    const int D  = in_sizes[0] / in_sizes[1];    // feature dim
    const int BT = out_size / D;                 // B*T total frames
    const int vecs = D >> 2;                     // float4s per row

    int* widx = (int*)d_ws;                      // BT ints of scratch

    // Kernel 1: per-frame index (~0.5 MB written, tiny)
    const int grid1 = (BT + 255) / 256;
    lr_index_kernel<<<grid1, 256, 0, stream>>>(dur, tlen, widx, BL, BT);

    // Kernel 2: streaming gather-copy
    const long n = (long)BT * vecs;
    int shift = -1;
    if ((vecs & (vecs - 1)) == 0) {              // pow2?
        shift = 0;
        while ((1 << shift) != vecs) ++shift;
    }
    const int grid2 = 2048;                      // 8 blocks/CU, 16 float4/thread
    if (shift >= 0) {
        lr_copy_kernel<<<grid2, 256, 0, stream>>>(
            (const float4*)feat, widx, (float4*)d_out, n, shift);
    } else {
        lr_copy_generic_kernel<<<grid2, 256, 0, stream>>>(
            (const float4*)feat, widx, (float4*)d_out, n, vecs);
    }
}

// Round 5
// 144.936 us; speedup vs baseline: 1.2783x; 1.2783x over previous
//
#include <hip/hip_runtime.h>

#define MAX_L 2048   // max phonemes per batch for LDS cumsum
#define MAX_EPC 8    // max cum elements per thread (L <= 256*8)
#define FPB 128      // frames per block

// Fused length-regulator, run-length store streaming.
// One 256-thread block per 128 output frames:
//   1) block computes its batch's duration cumsum in LDS (shuffle scan)
//   2) 128 threads binary-search in LDS -> sidx[128] (phoneme idx, -1 = pad)
//   3) each wave copies 32 CONTIGUOUS frames; the source row is held in
//      registers and reloaded only when the phoneme index changes (scalar
//      branch via readlane), so steady state is back-to-back coalesced
//      1 KiB stores with no load dependency — memset-shaped.
__global__ __launch_bounds__(256) void lr_fused_kernel(
        const float* __restrict__ feat,
        const int* __restrict__ dur,
        const int* __restrict__ tlen,
        float* __restrict__ out,
        int BL, int BT, int D) {
    const int T = *tlen;
    const int B = BT / T;
    const int L = BL / B;
    const int vecs = D >> 2;

    __shared__ int sc[MAX_L];
    __shared__ int swsum[4];
    __shared__ int sidx[FPB];

    const long frame_base0 = (long)blockIdx.x * FPB;
    if (frame_base0 >= BT) return;

    const int tid  = threadIdx.x;
    const int lane = tid & 63;
    const int wv   = tid >> 6;

    long fb_ = frame_base0;
    int remaining = (int)((long)BT - frame_base0 < FPB ? (long)BT - frame_base0
                                                       : (long)FPB);

    // Segment loop (block-uniform): one iteration in the common case
    // (T % FPB == 0); handles batch-straddling blocks correctly otherwise.
    while (remaining > 0) {
        const int b   = (int)(fb_ / T);
        const int tt0 = (int)(fb_ - (long)b * T);
        const int seg = remaining < (T - tt0) ? remaining : (T - tt0);

        // ---- cumsum of batch b's duration row into sc ----
        __syncthreads();  // protect sc/sidx reuse across segments
        const int epc  = (L + blockDim.x - 1) / blockDim.x;
        const int base = tid * epc;
        const int* __restrict__ drow = dur + (size_t)b * L;
        int local[MAX_EPC];
        int run = 0;
#pragma unroll
        for (int e = 0; e < MAX_EPC; ++e) {
            int v = 0;
            if (e < epc && base + e < L) v = drow[base + e];
            run += v;
            local[e] = run;
        }
        int wsum = run;
#pragma unroll
        for (int off = 1; off < 64; off <<= 1) {
            int up = __shfl_up(wsum, off, 64);
            if (lane >= off) wsum += up;
        }
        if (lane == 63) swsum[wv] = wsum;
        __syncthreads();
        int wprefix = 0;
        for (int w = 0; w < wv; ++w) wprefix += swsum[w];
        const int chunk_prefix = wprefix + wsum - run;
#pragma unroll
        for (int e = 0; e < MAX_EPC; ++e)
            if (e < epc && base + e < L) sc[base + e] = chunk_prefix + local[e];
        __syncthreads();

        const int total = sc[L - 1];

        // ---- searchsorted(side='right') for this segment's frames ----
        if (tid < seg) {
            const int t = tt0 + tid;
            int p = -1;
            if (t < total) {
                int lo = 0, hi = L - 1;
                while (lo < hi) {
                    const int mid = (lo + hi) >> 1;
                    if (sc[mid] > t) hi = mid;
                    else             lo = mid + 1;
                }
                p = lo;
            }
            sidx[tid] = p;
        }
        __syncthreads();

        // ---- copy ----
        if (seg == FPB && vecs == 64) {
            // Fast path (D == 256, full segment): wave wv owns 32 contiguous
            // frames. Row index made scalar via readlane; row data cached in
            // one float4/lane, reloaded only on index change (~2x per 32).
            const float4* __restrict__ fbp =
                (const float4*)feat + (size_t)b * L * 64;
            float4* __restrict__ op =
                (float4*)out + ((size_t)fb_ + (size_t)wv * 32) * 64 + lane;
            const int si = sidx[wv * 32 + (lane & 31)];  // lane j holds sidx[wv*32+j]
            int prev = -2;
            float4 v = make_float4(0.f, 0.f, 0.f, 0.f);
#pragma unroll
            for (int j = 0; j < 32; ++j) {
                const int p = __builtin_amdgcn_readlane(si, j);  // uniform (SGPR)
                if (p != prev) {                                  // scalar branch
                    v = (p >= 0) ? fbp[(size_t)p * 64 + lane]
                                 : make_float4(0.f, 0.f, 0.f, 0.f);
                    prev = p;
                }
                op[(size_t)j * 64] = v;   // back-to-back 1 KiB wave stores
            }
        } else {
            // Generic fallback: wave-strided frames, lane-strided float4s.
            const float4* __restrict__ fbp =
                (const float4*)feat + (size_t)b * L * vecs;
            const float4 z = make_float4(0.f, 0.f, 0.f, 0.f);
            for (int f = wv; f < seg; f += 4) {
                const int p = sidx[f];
                float4* __restrict__ orow = (float4*)out + ((size_t)fb_ + f) * vecs;
                if (p >= 0) {
                    const float4* __restrict__ irow = fbp + (size_t)p * vecs;
                    for (int i = lane; i < vecs; i += 64) orow[i] = irow[i];
                } else {
                    for (int i = lane; i < vecs; i += 64) orow[i] = z;
                }
            }
        }

        fb_ += seg;
        remaining -= seg;
    }
}

extern "C" void kernel_launch(void* const* d_in, const int* in_sizes, int n_in,
                              void* d_out, int out_size, void* d_ws, size_t ws_size,
                              hipStream_t stream) {
    const float* feat = (const float*)d_in[0];   // [B, L, D] fp32
    const int*   dur  = (const int*)d_in[1];     // [B, L] int32
    const int*   tlen = (const int*)d_in[2];     // scalar target_length (device)

    const int BL = in_sizes[1];                  // B*L
    const int D  = in_sizes[0] / in_sizes[1];    // feature dim
    const int BT = out_size / D;                 // B*T total frames

    const int grid = (BT + FPB - 1) / FPB;       // 1024 blocks for 16x8192
    lr_fused_kernel<<<grid, 256, 0, stream>>>(feat, dur, tlen, (float*)d_out,
                                              BL, BT, D);
}